// Round 3
// baseline (1680.025 us; speedup 1.0000x reference)
//
#include <hip/hip_runtime.h>

// ---------------------------------------------------------------------------
// HebbianBlock: out(B,T,D) f32; chunked linear-attention style recurrence.
// Pipeline: cast->bf16 | w^T transpose | vT = Ww@rk^T (GEMM) |
//           scan(inter, W-state, 16-wave, reg-direct + depth-4 prefetch,
//                bare barriers so vmem stays in flight) | intra |
//           y = out + alpha*(inter+intra)@Wr^T (GEMM)
// ---------------------------------------------------------------------------

typedef __attribute__((ext_vector_type(8))) short short8;
typedef __attribute__((ext_vector_type(4))) short short4v;
typedef __attribute__((ext_vector_type(4))) float f32x4;

#define B_ 4
#define T_ 8192
#define D_ 1024
#define C_ 64
#define NC_ 128

#define DEVI static __device__ __forceinline__

#define EXPF(x) __builtin_expf(x)
#define LOG2F(x) __builtin_log2f(x)
#define EXP2F(x) __builtin_exp2f(x)

DEVI unsigned short f2bf_u(float f) {
  unsigned int u = __float_as_uint(f);
  u += 0x7fffu + ((u >> 16) & 1u);   // round-to-nearest-even
  return (unsigned short)(u >> 16);
}
DEVI short f2bfs(float f) { return (short)f2bf_u(f); }
DEVI float bf2fs(short h) { return __uint_as_float(((unsigned int)(unsigned short)h) << 16); }

DEVI f32x4 mfma16(short8 a, short8 b, f32x4 c) {
  return __builtin_amdgcn_mfma_f32_16x16x32_bf16(a, b, c, 0, 0, 0);
}

// bare workgroup barrier: drain ONLY our LDS ops (writes must be visible to
// other waves), leave global register-loads in flight (no vmcnt(0) drain).
DEVI void chunk_barrier() {
  asm volatile("s_waitcnt lgkmcnt(0)" ::: "memory");
  __builtin_amdgcn_s_barrier();
}

// ---------------------------------------------------------------- cast f32->bf16
__global__ __launch_bounds__(256) void k_cast(const float* __restrict__ src,
                                              short* __restrict__ dst, int n8) {
  int i = blockIdx.x * 256 + threadIdx.x;
  if (i >= n8) return;
  const float4* s = (const float4*)src;
  float4 a = s[2 * i], b = s[2 * i + 1];
  short8 o;
  o[0] = f2bfs(a.x); o[1] = f2bfs(a.y); o[2] = f2bfs(a.z); o[3] = f2bfs(a.w);
  o[4] = f2bfs(b.x); o[5] = f2bfs(b.y); o[6] = f2bfs(b.z); o[7] = f2bfs(b.w);
  *((short8*)dst + i) = o;
}

// ---------------------------------------------------------------- w^T transpose
// wTg[b][e][t] = rk[b][t-1][e]  (pre-shifted: w_t = rk_{t-1}, t=0 -> 0)
__global__ __launch_bounds__(256) void k_transT(const short* __restrict__ rk,
                                                short* __restrict__ wTg) {
  __shared__ short ts[64][72];
  const int tid = threadIdx.x;
  const int t0 = blockIdx.x * 64, e0 = blockIdx.y * 64, b = blockIdx.z;
  const short* rk_b = rk + (size_t)b * T_ * D_;
  short* w_b = wTg + (size_t)b * D_ * T_;
  const int lr = tid >> 3, ls = tid & 7;   // 32 rows x 8 segs per pass
#pragma unroll
  for (int p = 0; p < 2; ++p) {
    int row = p * 32 + lr;                 // ts[row] holds rk[t0-1+row]
    int t = t0 - 1 + row;
    short8 v8;
    if (t >= 0) v8 = *(const short8*)(rk_b + (size_t)t * D_ + e0 + ls * 8);
    else v8 = (short8){0, 0, 0, 0, 0, 0, 0, 0};
    *(short8*)&ts[row][ls * 8] = v8;
  }
  __syncthreads();
  const int er5 = tid & 31, thi = tid >> 5;   // erow low-bits for bank spread
#pragma unroll
  for (int ep = 0; ep < 2; ++ep) {
    int erow = ep * 32 + er5;
    short8 w8;
#pragma unroll
    for (int j = 0; j < 8; ++j) w8[j] = ts[thi * 8 + j][erow];
    *(short8*)(w_b + (size_t)(e0 + erow) * T_ + t0 + thi * 8) = w8;
  }
}

// ---------------------------------------------------------------- vT = Ww @ rk^T
__global__ __launch_bounds__(256) void k_gemm_v(const short* __restrict__ Aw,
                                                const short* __restrict__ Bx,
                                                short* __restrict__ vT) {
  __shared__ short As[128][72];
  __shared__ short Bs[128][72];
  const int tid = threadIdx.x;
  const int lane = tid & 63, wv = tid >> 6;
  const int wm = (wv >> 1) * 64, wn = (wv & 1) * 64;
  const int l16 = lane & 15, q = lane >> 4;
  const int m0 = blockIdx.y * 128;
  const int n0 = blockIdx.x * 128;
  f32x4 acc[4][4];
  for (int a = 0; a < 4; ++a)
    for (int b = 0; b < 4; ++b) acc[a][b] = (f32x4){0.f, 0.f, 0.f, 0.f};
  const int lrow = tid >> 3, lseg = tid & 7;
  const short* Ap = Aw + (size_t)(m0 + lrow) * D_ + lseg * 8;
  const short* Bp = Bx + (size_t)(n0 + lrow) * D_ + lseg * 8;
  for (int kb = 0; kb < D_; kb += 64) {
#pragma unroll
    for (int p = 0; p < 4; ++p) {
      *(short8*)&As[lrow + p * 32][lseg * 8] = *(const short8*)(Ap + (size_t)(p * 32) * D_ + kb);
      *(short8*)&Bs[lrow + p * 32][lseg * 8] = *(const short8*)(Bp + (size_t)(p * 32) * D_ + kb);
    }
    __syncthreads();
#pragma unroll
    for (int ks = 0; ks < 2; ++ks) {
      short8 af[4], bfr[4];
#pragma unroll
      for (int mt = 0; mt < 4; ++mt) af[mt] = *(const short8*)&As[wm + mt * 16 + l16][ks * 32 + q * 8];
#pragma unroll
      for (int nt = 0; nt < 4; ++nt) bfr[nt] = *(const short8*)&Bs[wn + nt * 16 + l16][ks * 32 + q * 8];
#pragma unroll
      for (int mt = 0; mt < 4; ++mt)
#pragma unroll
        for (int nt = 0; nt < 4; ++nt) acc[mt][nt] = mfma16(af[mt], bfr[nt], acc[mt][nt]);
    }
    __syncthreads();
  }
  const int b = n0 >> 13;                // T_ = 8192 rows per batch
  const int tbase = (n0 & (T_ - 1)) + wn;
  short* outp = vT + (size_t)b * D_ * T_;
#pragma unroll
  for (int mt = 0; mt < 4; ++mt)
#pragma unroll
    for (int nt = 0; nt < 4; ++nt)
#pragma unroll
      for (int i = 0; i < 4; ++i) {
        int d = m0 + wm + mt * 16 + q * 4 + i;
        int t = tbase + nt * 16 + l16;
        outp[(size_t)d * T_ + t] = f2bfs(acc[mt][nt][i]);
      }
}

// ---------------------------------------------------------------- scan (inter + W state)
// grid (64 d-tiles, 4 batches), 1024 threads (16 waves).
// MFMA fragments read DIRECTLY from global (L2/L3-resident), prefetched ONE
// FULL CHUNK (4 slice-groups) ahead into registers.  Chunk-end barriers are
// bare s_barrier + lgkmcnt(0) only, so prefetch loads stay in flight across
// the chunk boundary (no vmcnt(0) drain).
__global__ __launch_bounds__(1024, 4) void k_scan(const short* __restrict__ rk,
                                                  const short* __restrict__ vT_g,
                                                  const short* __restrict__ wTg,
                                                  short* __restrict__ inter_,
                                                  const float* __restrict__ decay_p) {
  __shared__ short Wb[16][1032];     // bf16 snapshot of W[d][e] (chunk-start value)
  __shared__ short vTs[16][72];      // v^T slice scaled by gw[c]=gamma^(63-c)
  __shared__ float red[8][64][20];   // inter^T partials: [e-range][c][d(16)+pad]

  const int tid = threadIdx.x;
  const int lane = tid & 63;
  const int wv = tid >> 6;                 // 0..15
  const int l16 = lane & 15, q = lane >> 4;
  const int dt = blockIdx.x, b = blockIdx.y;
  const int d0 = dt * 16;
  const float gamma = 1.f / (1.f + EXPF(-decay_p[0]));
  const float lg2g = LOG2F(gamma);
  const float gC = EXP2F(64.f * lg2g);

  const short* rk_b = rk + (size_t)b * T_ * D_;
  const short* wT_b = wTg + (size_t)b * D_ * T_;
  const short* vT_b = vT_g + (size_t)b * D_ * T_;

  const int ew = (wv >> 1) * 32;           // GEMM1 e-range within each 256-slice
  const int cpair = (wv & 1) * 2;          // GEMM1 c-tile base (2 tiles)

  // fragment base pointers (per-wave constant)
  // af: rk[ch*64 + (cpair+u)*16 + l16][s*256 + ew + q*8]     (B-frag of GEMM1)
  const short* af_base = rk_b + (size_t)(cpair * 16 + l16) * D_ + ew + q * 8;
  // bw: wTg[s*256 + wv*16 + l16][ch*64 + ks*32 + q*8]        (A-frag of GEMM2)
  const short* bw_base = wT_b + (size_t)(wv * 16 + l16) * T_ + q * 8;

  // vTs staging role: threads [512,768)
  const bool vrole = (tid >= 512 && tid < 768);
  const int vd = (tid - 512) >> 4;
  const int vc4 = ((tid - 512) & 15) << 2;
  const short* vptr = vT_b + (size_t)(d0 + vd) * T_ + vc4;
  short4v vpre;

  f32x4 Wacc[4];                     // W^T[e=s2*256+wv*16+q*4+i][d=l16]
#pragma unroll
  for (int j = 0; j < 4; ++j) Wacc[j] = (f32x4){0.f, 0.f, 0.f, 0.f};
  f32x4 iacc[2];                     // inter^T[d=q*4+i][c=(cpair+u)*16+l16]
  iacc[0] = (f32x4){0.f, 0.f, 0.f, 0.f};
  iacc[1] = (f32x4){0.f, 0.f, 0.f, 0.f};

  // depth-4 prefetch buffers (one per slice; statically indexed via unroll)
  short8 pA0[4], pA1[4], pW0[4], pW1[4];
  auto issue = [&](int ch, int s, short8& a0, short8& a1, short8& w0, short8& w1) {
    const short* a = af_base + (size_t)(ch * 64) * D_ + s * 256;
    a0 = *(const short8*)a;
    a1 = *(const short8*)(a + (size_t)16 * D_);
    const short* w = bw_base + (size_t)(s * 256) * T_ + ch * 64;
    w0 = *(const short8*)w;
    w1 = *(const short8*)(w + 32);
  };
  auto write_vTs = [&]() {
#pragma unroll
    for (int j = 0; j < 4; ++j)
      vTs[vd][vc4 + j] = f2bfs(bf2fs(vpre[j]) * EXP2F(lg2g * (float)(63 - (vc4 + j))));
  };

  // ---- prologue: fill all 4 prefetch buffers with chunk 0
#pragma unroll
  for (int s = 0; s < 4; ++s) issue(0, s, pA0[s], pA1[s], pW0[s], pW1[s]);
  if (vrole) vpre = *(const short4v*)vptr;
  {
    short4v z4 = (short4v){0, 0, 0, 0};
    for (int i = tid; i < (16 * 1032) / 4; i += 1024) ((short4v*)&Wb[0][0])[i] = z4;
  }
  if (vrole) write_vTs();
  __syncthreads();

  for (int ch = 0; ch < NC_; ++ch) {
    const int chn = (ch + 1 < NC_) ? ch + 1 : ch;   // clamp (last-chunk reload unused)
    // v^T B-fragments (vg[d=l16][c]) held in regs for the whole chunk
    short8 a2k0 = *(const short8*)&vTs[l16][q * 8];
    short8 a2k1 = *(const short8*)&vTs[l16][32 + q * 8];
    // issue next chunk's vpre early (consumed at epilogue -> full-chunk cover)
    if (vrole) vpre = *(const short4v*)(vptr + chn * 64);
#pragma unroll
    for (int s = 0; s < 4; ++s) {
      short8 af0 = pA0[s], af1 = pA1[s], bw0 = pW0[s], bw1 = pW1[s];
      // refill this slot with chunk ch+1 (prefetch distance = 4 groups)
      issue(chn, s, pA0[s], pA1[s], pW0[s], pW1[s]);
      short8 bfr = *(const short8*)&Wb[l16][s * 256 + ew + q * 8];
      // GEMM1: inter^T += Wb-frag (A) x rk-frag (B)
      iacc[0] = mfma16(bfr, af0, iacc[0]);
      iacc[1] = mfma16(bfr, af1, iacc[1]);
      // GEMM2: W^T[e][d] += wT-frag (A) x vg-frag (B)
      Wacc[s] = mfma16(bw0, a2k0, Wacc[s]);
      Wacc[s] = mfma16(bw1, a2k1, Wacc[s]);
    }
    chunk_barrier();                 // 1: all Wb/vTs reads of this chunk done
    // ---- chunk epilogue ----
    // inter^T partial dump (b128) + reset
#pragma unroll
    for (int u = 0; u < 2; ++u) {
      *(f32x4*)&red[wv >> 1][(cpair + u) * 16 + l16][q * 4] = iacc[u];
      iacc[u] = (f32x4){0.f, 0.f, 0.f, 0.f};
    }
    // W snapshot (pre-decay) -> Wb[d][e], b64 per s2; then decay state
#pragma unroll
    for (int s2 = 0; s2 < 4; ++s2) {
      short4v w4;
#pragma unroll
      for (int i = 0; i < 4; ++i) w4[i] = f2bfs(Wacc[s2][i]);
      *(short4v*)&Wb[l16][s2 * 256 + wv * 16 + q * 4] = w4;
#pragma unroll
      for (int i = 0; i < 4; ++i) Wacc[s2][i] *= gC;
    }
    // stage next chunk's scaled v^T
    if (vrole && ch + 1 < NC_) write_vTs();
    chunk_barrier();                 // 2: Wb/red/vTs writes visible
    // reduce 8 e-range partials (4 waves; overlaps with next chunk's compute)
    if (tid < 256) {
      int c = tid >> 2, dq = tid & 3;
      f32x4 sum = *(const f32x4*)&red[0][c][dq * 4];
#pragma unroll
      for (int p = 1; p < 8; ++p) sum += *(const f32x4*)&red[p][c][dq * 4];
      float sc = EXP2F(lg2g * (float)c);
      short4v o;
#pragma unroll
      for (int i = 0; i < 4; ++i) o[i] = f2bfs(sum[i] * sc);
      *(short4v*)(inter_ + (size_t)b * T_ * D_ + (size_t)(ch * 64 + c) * D_ + d0 + dq * 4) = o;
    }
  }
}

// ---------------------------------------------------------------- intra chunk
__global__ __launch_bounds__(256) void k_intra(const short* __restrict__ rk,
                                               const short* __restrict__ vT_g,
                                               short* __restrict__ intra_,
                                               const float* __restrict__ decay_p) {
  __shared__ short rs[65][264];
  __shared__ short P[64][72];
  __shared__ short vs[256][72];
  const int tid = threadIdx.x;
  const int lane = tid & 63, wv = tid >> 6;
  const int l16 = lane & 15, q = lane >> 4;
  const int ch = blockIdx.x, b = blockIdx.y;
  const int t0 = ch << 6;
  const float gamma = 1.f / (1.f + EXPF(-decay_p[0]));
  const float lg2g = LOG2F(gamma);
  const short* rk_b = rk + (size_t)b * T_ * D_;
  f32x4 Sacc[4];
#pragma unroll
  for (int j = 0; j < 4; ++j) Sacc[j] = (f32x4){0.f, 0.f, 0.f, 0.f};

  for (int s = 0; s < 4; ++s) {
    const int e0 = s << 8;
#pragma unroll
    for (int p = 0; p < 9; ++p) {
      int idx = p * 256 + tid;
      if (idx < 2080) {
        int row = idx >> 5, seg = idx & 31;
        int t = t0 - 1 + row;
        short8 v8;
        if (t >= 0) v8 = *(const short8*)(rk_b + (size_t)t * D_ + e0 + seg * 8);
        else v8 = (short8){0, 0, 0, 0, 0, 0, 0, 0};
        *(short8*)&rs[row][seg * 8] = v8;
      }
    }
    __syncthreads();
#pragma unroll
    for (int ks = 0; ks < 8; ++ks) {
      short8 af = *(const short8*)&rs[wv * 16 + l16 + 1][ks * 32 + q * 8];   // r rows
#pragma unroll
      for (int nt = 0; nt < 4; ++nt) {
        short8 bfr = *(const short8*)&rs[nt * 16 + l16][ks * 32 + q * 8];    // w rows
        Sacc[nt] = mfma16(af, bfr, Sacc[nt]);
      }
    }
    __syncthreads();
  }
  // mask: P[c][c'] = S * gamma^(c-1-c') for c>c', else 0
#pragma unroll
  for (int nt = 0; nt < 4; ++nt)
#pragma unroll
    for (int i = 0; i < 4; ++i) {
      int c = wv * 16 + q * 4 + i;
      int cp = nt * 16 + l16;
      float m = (c > cp) ? EXP2F(lg2g * (float)(c - 1 - cp)) : 0.f;
      P[c][cp] = f2bfs(Sacc[nt][i] * m);
    }
  __syncthreads();
  const short* vsrc = vT_g + (size_t)b * D_ * T_ + (size_t)tid * T_ + t0;
  size_t base = (size_t)b * T_ * D_;
  for (int p = 0; p < 4; ++p) {
    const short* sp = vsrc + (size_t)(p * 256) * T_;
#pragma unroll
    for (int seg = 0; seg < 8; ++seg)
      *(short8*)&vs[tid][seg * 8] = *(const short8*)(sp + seg * 8);
    __syncthreads();
    f32x4 acc[4][4];
#pragma unroll
    for (int a = 0; a < 4; ++a)
#pragma unroll
      for (int bb = 0; bb < 4; ++bb) acc[a][bb] = (f32x4){0.f, 0.f, 0.f, 0.f};
#pragma unroll
    for (int ks2 = 0; ks2 < 2; ++ks2) {
      short8 af[4];
#pragma unroll
      for (int mt = 0; mt < 4; ++mt) af[mt] = *(const short8*)&P[mt * 16 + l16][ks2 * 32 + q * 8];
#pragma unroll
      for (int nt = 0; nt < 4; ++nt) {
        short8 bfr = *(const short8*)&vs[wv * 64 + nt * 16 + l16][ks2 * 32 + q * 8];
#pragma unroll
        for (int mt = 0; mt < 4; ++mt) acc[mt][nt] = mfma16(af[mt], bfr, acc[mt][nt]);
      }
    }
#pragma unroll
    for (int mt = 0; mt < 4; ++mt)
#pragma unroll
      for (int nt = 0; nt < 4; ++nt)
#pragma unroll
        for (int i = 0; i < 4; ++i) {
          int c = mt * 16 + q * 4 + i;
          int d = p * 256 + wv * 64 + nt * 16 + l16;
          intra_[base + (size_t)(t0 + c) * D_ + d] = f2bfs(acc[mt][nt][i]);
        }
    __syncthreads();
  }
}

// ---------------------------------------------------------------- final GEMM
__global__ __launch_bounds__(256) void k_gemm_final(const short* __restrict__ inter_,
                                                    const short* __restrict__ intra_,
                                                    const short* __restrict__ Wr,
                                                    const float* __restrict__ xin,
                                                    float* __restrict__ y,
                                                    const float* __restrict__ la_p) {
  __shared__ short As[128][72];
  __shared__ short Bs[128][72];
  const float alpha = EXPF(la_p[0]);
  const int tid = threadIdx.x;
  const int lane = tid & 63, wv = tid >> 6;
  const int wm = (wv >> 1) * 64, wn = (wv & 1) * 64;
  const int l16 = lane & 15, q = lane >> 4;
  const int m0 = blockIdx.x * 128;
  const int n0 = blockIdx.y * 128;
  f32x4 acc[4][4];
  for (int a = 0; a < 4; ++a)
    for (int b = 0; b < 4; ++b) acc[a][b] = (f32x4){0.f, 0.f, 0.f, 0.f};
  const int lrow = tid >> 3, lseg = tid & 7;
  for (int kb = 0; kb < D_; kb += 64) {
#pragma unroll
    for (int p = 0; p < 4; ++p) {
      size_t aoff = (size_t)(m0 + lrow + p * 32) * D_ + kb + lseg * 8;
      short8 xa = *(const short8*)(inter_ + aoff);
      short8 xb = *(const short8*)(intra_ + aoff);
      short8 xs;
#pragma unroll
      for (int j = 0; j < 8; ++j) xs[j] = f2bfs(bf2fs(xa[j]) + bf2fs(xb[j]));
      *(short8*)&As[lrow + p * 32][lseg * 8] = xs;
      *(short8*)&Bs[lrow + p * 32][lseg * 8] =
          *(const short8*)(Wr + (size_t)(n0 + lrow + p * 32) * D_ + kb + lseg * 8);
    }
    __syncthreads();
#pragma unroll
    for (int ks = 0; ks < 2; ++ks) {
      short8 af[4], bfr[4];
#pragma unroll
      for (int mt = 0; mt < 4; ++mt) af[mt] = *(const short8*)&As[wm + mt * 16 + l16][ks * 32 + q * 8];
#pragma unroll
      for (int nt = 0; nt < 4; ++nt) bfr[nt] = *(const short8*)&Bs[wn + nt * 16 + l16][ks * 32 + q * 8];
#pragma unroll
      for (int mt = 0; mt < 4; ++mt)
#pragma unroll
        for (int nt = 0; nt < 4; ++nt) acc[mt][nt] = mfma16(af[mt], bfr[nt], acc[mt][nt]);
    }
    __syncthreads();
  }
#pragma unroll
  for (int mt = 0; mt < 4; ++mt)
#pragma unroll
    for (int nt = 0; nt < 4; ++nt)
#pragma unroll
      for (int i = 0; i < 4; ++i) {
        int t = m0 + wm + mt * 16 + q * 4 + i;
        int d = n0 + wn + nt * 16 + l16;
        size_t idx = (size_t)t * D_ + d;
        y[idx] = xin[idx] + alpha * acc[mt][nt][i];
      }
}

// ---------------------------------------------------------------- launch
extern "C" void kernel_launch(void* const* d_in, const int* in_sizes, int n_in,
                              void* d_out, int out_size, void* d_ws, size_t ws_size,
                              hipStream_t stream) {
  const float* x = (const float*)d_in[0];
  const float* Ww = (const float*)d_in[1];
  const float* Wr = (const float*)d_in[2];
  const float* decay = (const float*)d_in[3];
  const float* log_alpha = (const float*)d_in[4];
  float* y = (float*)d_out;

  short* ws = (short*)d_ws;
  const size_t NTD = (size_t)B_ * T_ * D_;   // 33,554,432
  short* rk_bf = ws;
  short* vT_bf = rk_bf + NTD;
  short* inter_b = vT_bf + NTD;
  short* intra_b = inter_b + NTD;
  short* Ww_bf = intra_b + NTD;
  short* Wr_bf = Ww_bf + (size_t)D_ * D_;
  // wTg aliases intra_b: only live between k_transT and k_scan; k_intra
  // overwrites it afterwards. total ws use unchanged: 4*NTD + 2*D*D shorts.
  short* wTg = intra_b;

  k_cast<<<(int)(NTD / 8 / 256), 256, 0, stream>>>(x, rk_bf, (int)(NTD / 8));
  k_cast<<<512, 256, 0, stream>>>(Ww, Ww_bf, (D_ * D_) / 8);
  k_cast<<<512, 256, 0, stream>>>(Wr, Wr_bf, (D_ * D_) / 8);
  k_transT<<<dim3(T_ / 64, D_ / 64, B_), 256, 0, stream>>>(rk_bf, wTg);
  k_gemm_v<<<dim3(256, 8), 256, 0, stream>>>(Ww_bf, rk_bf, vT_bf);
  k_scan<<<dim3(64, 4), 1024, 0, stream>>>(rk_bf, vT_bf, wTg, inter_b, decay);
  k_intra<<<dim3(128, 4), 256, 0, stream>>>(rk_bf, vT_bf, intra_b, decay);
  k_gemm_final<<<dim3(256, 8), 256, 0, stream>>>(inter_b, intra_b, Wr_bf, x, y, log_alpha);
}

// Round 5
// 1278.836 us; speedup vs baseline: 1.3137x; 1.3137x over previous
//
#include <hip/hip_runtime.h>

// ---------------------------------------------------------------------------
// HebbianBlock: out(B,T,D) f32; chunked linear-attention style recurrence.
// Pipeline: cast->bf16 | w^T transpose | vT = Ww@rk^T (GEMM) |
//           scan(inter, W-state, 16-wave, LDS dbuf, 1 barrier/group) | intra |
//           y = out + alpha*(inter+intra)@Wr^T (GEMM)
// ---------------------------------------------------------------------------

typedef __attribute__((ext_vector_type(8))) short short8;
typedef __attribute__((ext_vector_type(4))) short short4v;
typedef __attribute__((ext_vector_type(4))) float f32x4;

#define B_ 4
#define T_ 8192
#define D_ 1024
#define C_ 64
#define NC_ 128

#define DEVI static __device__ __forceinline__

#define EXPF(x) __builtin_expf(x)
#define LOG2F(x) __builtin_log2f(x)
#define EXP2F(x) __builtin_exp2f(x)

DEVI unsigned short f2bf_u(float f) {
  unsigned int u = __float_as_uint(f);
  u += 0x7fffu + ((u >> 16) & 1u);   // round-to-nearest-even
  return (unsigned short)(u >> 16);
}
DEVI short f2bfs(float f) { return (short)f2bf_u(f); }
DEVI float bf2fs(short h) { return __uint_as_float(((unsigned int)(unsigned short)h) << 16); }

DEVI f32x4 mfma16(short8 a, short8 b, f32x4 c) {
  return __builtin_amdgcn_mfma_f32_16x16x32_bf16(a, b, c, 0, 0, 0);
}

// ---------------------------------------------------------------- cast f32->bf16
__global__ __launch_bounds__(256) void k_cast(const float* __restrict__ src,
                                              short* __restrict__ dst, int n8) {
  int i = blockIdx.x * 256 + threadIdx.x;
  if (i >= n8) return;
  const float4* s = (const float4*)src;
  float4 a = s[2 * i], b = s[2 * i + 1];
  short8 o;
  o[0] = f2bfs(a.x); o[1] = f2bfs(a.y); o[2] = f2bfs(a.z); o[3] = f2bfs(a.w);
  o[4] = f2bfs(b.x); o[5] = f2bfs(b.y); o[6] = f2bfs(b.z); o[7] = f2bfs(b.w);
  *((short8*)dst + i) = o;
}

// ---------------------------------------------------------------- w^T transpose
// wTg[b][e][t] = rk[b][t-1][e]  (pre-shifted: w_t = rk_{t-1}, t=0 -> 0)
__global__ __launch_bounds__(256) void k_transT(const short* __restrict__ rk,
                                                short* __restrict__ wTg) {
  __shared__ short ts[64][72];
  const int tid = threadIdx.x;
  const int t0 = blockIdx.x * 64, e0 = blockIdx.y * 64, b = blockIdx.z;
  const short* rk_b = rk + (size_t)b * T_ * D_;
  short* w_b = wTg + (size_t)b * D_ * T_;
  const int lr = tid >> 3, ls = tid & 7;   // 32 rows x 8 segs per pass
#pragma unroll
  for (int p = 0; p < 2; ++p) {
    int row = p * 32 + lr;                 // ts[row] holds rk[t0-1+row]
    int t = t0 - 1 + row;
    short8 v8;
    if (t >= 0) v8 = *(const short8*)(rk_b + (size_t)t * D_ + e0 + ls * 8);
    else v8 = (short8){0, 0, 0, 0, 0, 0, 0, 0};
    *(short8*)&ts[row][ls * 8] = v8;
  }
  __syncthreads();
  const int er5 = tid & 31, thi = tid >> 5;   // erow low-bits for bank spread
#pragma unroll
  for (int ep = 0; ep < 2; ++ep) {
    int erow = ep * 32 + er5;
    short8 w8;
#pragma unroll
    for (int j = 0; j < 8; ++j) w8[j] = ts[thi * 8 + j][erow];
    *(short8*)(w_b + (size_t)(e0 + erow) * T_ + t0 + thi * 8) = w8;
  }
}

// ---------------------------------------------------------------- vT = Ww @ rk^T
__global__ __launch_bounds__(256) void k_gemm_v(const short* __restrict__ Aw,
                                                const short* __restrict__ Bx,
                                                short* __restrict__ vT) {
  __shared__ short As[128][72];
  __shared__ short Bs[128][72];
  const int tid = threadIdx.x;
  const int lane = tid & 63, wv = tid >> 6;
  const int wm = (wv >> 1) * 64, wn = (wv & 1) * 64;
  const int l16 = lane & 15, q = lane >> 4;
  const int m0 = blockIdx.y * 128;
  const int n0 = blockIdx.x * 128;
  f32x4 acc[4][4];
  for (int a = 0; a < 4; ++a)
    for (int b = 0; b < 4; ++b) acc[a][b] = (f32x4){0.f, 0.f, 0.f, 0.f};
  const int lrow = tid >> 3, lseg = tid & 7;
  const short* Ap = Aw + (size_t)(m0 + lrow) * D_ + lseg * 8;
  const short* Bp = Bx + (size_t)(n0 + lrow) * D_ + lseg * 8;
  for (int kb = 0; kb < D_; kb += 64) {
#pragma unroll
    for (int p = 0; p < 4; ++p) {
      *(short8*)&As[lrow + p * 32][lseg * 8] = *(const short8*)(Ap + (size_t)(p * 32) * D_ + kb);
      *(short8*)&Bs[lrow + p * 32][lseg * 8] = *(const short8*)(Bp + (size_t)(p * 32) * D_ + kb);
    }
    __syncthreads();
#pragma unroll
    for (int ks = 0; ks < 2; ++ks) {
      short8 af[4], bfr[4];
#pragma unroll
      for (int mt = 0; mt < 4; ++mt) af[mt] = *(const short8*)&As[wm + mt * 16 + l16][ks * 32 + q * 8];
#pragma unroll
      for (int nt = 0; nt < 4; ++nt) bfr[nt] = *(const short8*)&Bs[wn + nt * 16 + l16][ks * 32 + q * 8];
#pragma unroll
      for (int mt = 0; mt < 4; ++mt)
#pragma unroll
        for (int nt = 0; nt < 4; ++nt) acc[mt][nt] = mfma16(af[mt], bfr[nt], acc[mt][nt]);
    }
    __syncthreads();
  }
  const int b = n0 >> 13;                // T_ = 8192 rows per batch
  const int tbase = (n0 & (T_ - 1)) + wn;
  short* outp = vT + (size_t)b * D_ * T_;
#pragma unroll
  for (int mt = 0; mt < 4; ++mt)
#pragma unroll
    for (int nt = 0; nt < 4; ++nt)
#pragma unroll
      for (int i = 0; i < 4; ++i) {
        int d = m0 + wm + mt * 16 + q * 4 + i;
        int t = tbase + nt * 16 + l16;
        outp[(size_t)d * T_ + t] = f2bfs(acc[mt][nt][i]);
      }
}

// ---------------------------------------------------------------- scan (inter + W state)
// grid (64 d-tiles, 4 batches), 1024 threads (16 waves).
// Per chunk: 8 slice-groups of 128 e.  rs (r rows) and wT (w^T rows) staged
// global->reg->LDS, double-buffered, ONE barrier per group (disjoint buffers).
// GEMM1 (inter^T): wave wv -> c-tile (wv&3), k-range (wv>>2); 4-way LDS reduce.
// GEMM2 (W^T state): wave wv owns e in [wv*64, wv*64+64); active only in its
// slice (wv>>1), 8 MFMAs there.
__global__ __launch_bounds__(1024, 4) void k_scan(const short* __restrict__ rk,
                                                  const short* __restrict__ vT_g,
                                                  const short* __restrict__ wTg,
                                                  short* __restrict__ inter_,
                                                  const float* __restrict__ decay_p) {
  __shared__ short rs[2][64][136];   // r rows (c), 128-e slice + pad
  __shared__ short wT[2][128][72];   // w^T rows (e), 64 c + pad
  __shared__ short Wb[16][1032];     // bf16 snapshot of W[d][e] (chunk-start)
  __shared__ short vTs[16][72];      // v^T slice scaled by gw[c]=gamma^(63-c)
  __shared__ float red[4][64][20];   // inter^T partials: [k-range][c][d16+pad]

  const int tid = threadIdx.x;
  const int lane = tid & 63;
  const int wv = tid >> 6;                 // 0..15
  const int l16 = lane & 15, q = lane >> 4;
  const int dt = blockIdx.x, b = blockIdx.y;
  const int d0 = dt * 16;
  const float gamma = 1.f / (1.f + EXPF(-decay_p[0]));
  const float lg2g = LOG2F(gamma);
  const float gC = EXP2F(64.f * lg2g);

  const short* rk_b = rk + (size_t)b * T_ * D_;
  const short* wT_b = wTg + (size_t)b * D_ * T_;
  const short* vT_b = vT_g + (size_t)b * D_ * T_;

  const int ct = wv & 3;                   // GEMM1 c-tile
  const int kr = wv >> 2;                  // GEMM1 k-range (32 e within slice)
  const int sown = wv >> 1;                // GEMM2: active slice
  const int eo = (wv & 1) * 64;            // GEMM2: e-offset within slice

  // staging geometry (1024 threads move 16 KB rs + 16 KB wT per group)
  const int arow = tid >> 4, aseg = tid & 15;   // rs: 64 rows x 256 B
  const int wrow = tid >> 3, wseg = tid & 7;    // wT: 128 rows x 128 B
  const short* aG = rk_b + (size_t)arow * D_ + aseg * 8;
  const short* wG = wT_b + (size_t)wrow * T_ + wseg * 8;

  // vTs staging role: threads [512,768)
  const bool vrole = (tid >= 512 && tid < 768);
  const int vd = (tid - 512) >> 4;
  const int vc4 = ((tid - 512) & 15) << 2;
  const short* vptr = vT_b + (size_t)(d0 + vd) * T_ + vc4;
  short4v vpre;

  f32x4 Wacc[4];                     // W^T[e = wv*64 + et*16 + q*4 + i][d = l16]
#pragma unroll
  for (int j = 0; j < 4; ++j) Wacc[j] = (f32x4){0.f, 0.f, 0.f, 0.f};
  f32x4 iacc = (f32x4){0.f, 0.f, 0.f, 0.f};  // inter^T[d=q*4+i][c=ct*16+l16]

  short8 pfA, pfW;
  auto issue = [&](int g) {                // g = ch*8 + s
    int ch = g >> 3, s = g & 7;
    pfA = *(const short8*)(aG + (size_t)(ch * 64) * D_ + s * 128);
    pfW = *(const short8*)(wG + (size_t)(s * 128) * T_ + ch * 64);
  };
  auto write_pf = [&](int buf) {
    *(short8*)&rs[buf][arow][aseg * 8] = pfA;
    *(short8*)&wT[buf][wrow][wseg * 8] = pfW;
  };
  auto write_vTs = [&]() {
#pragma unroll
    for (int j = 0; j < 4; ++j)
      vTs[vd][vc4 + j] = f2bfs(bf2fs(vpre[j]) * EXP2F(lg2g * (float)(63 - (vc4 + j))));
  };

  // ---- prologue: stage group 0, init Wb=0, vTs(ch0)
  issue(0);
  if (vrole) vpre = *(const short4v*)vptr;
  write_pf(0);
  if (vrole) write_vTs();
  {
    short4v z4 = (short4v){0, 0, 0, 0};
    for (int i = tid; i < (16 * 1032) / 4; i += 1024) ((short4v*)&Wb[0][0])[i] = z4;
  }
  __syncthreads();

  short8 a2k0, a2k1;
  for (int g = 0; g < NC_ * 8; ++g) {
    const int ch = g >> 3, s = g & 7, cur = g & 1;
    if (s == 0) {
      // hoist v^T B-fragments for this chunk; start next chunk's v load
      a2k0 = *(const short8*)&vTs[l16][q * 8];
      a2k1 = *(const short8*)&vTs[l16][32 + q * 8];
      if (vrole) {
        int chn = (ch + 1 < NC_) ? ch + 1 : ch;
        vpre = *(const short4v*)(vptr + chn * 64);
      }
    }
    // issue next group's staging loads (one group of latency cover)
    if (g + 1 < NC_ * 8) issue(g + 1);
    // GEMM1: inter^T += Wb-frag (A, d rows) x r-frag (B, c rows)
    {
      short8 af = *(const short8*)&rs[cur][ct * 16 + l16][kr * 32 + q * 8];
      short8 bfr = *(const short8*)&Wb[l16][s * 128 + kr * 32 + q * 8];
      iacc = mfma16(bfr, af, iacc);
    }
    // GEMM2: W^T[e][d] += wT-frag (A, e rows) x vg-frag (B, d rows)
    if (sown == s) {
#pragma unroll
      for (int et = 0; et < 4; ++et) {
        short8 bw0 = *(const short8*)&wT[cur][eo + et * 16 + l16][q * 8];
        short8 bw1 = *(const short8*)&wT[cur][eo + et * 16 + l16][32 + q * 8];
        Wacc[et] = mfma16(bw0, a2k0, Wacc[et]);
        Wacc[et] = mfma16(bw1, a2k1, Wacc[et]);
      }
    }
    if (s < 7) {
      if (g + 1 < NC_ * 8) write_pf((g + 1) & 1);
      __syncthreads();
    } else {
      __syncthreads();                 // #1: all Wb/wT/rs reads of chunk done
      // ---- chunk epilogue ----
      // inter^T partial dump + reset
      *(f32x4*)&red[kr][ct * 16 + l16][q * 4] = iacc;
      iacc = (f32x4){0.f, 0.f, 0.f, 0.f};
      // W snapshot (pre-decay) -> Wb[d][e]; then decay state
#pragma unroll
      for (int et = 0; et < 4; ++et) {
        short4v w4;
#pragma unroll
        for (int i = 0; i < 4; ++i) w4[i] = f2bfs(Wacc[et][i]);
        *(short4v*)&Wb[l16][wv * 64 + et * 16 + q * 4] = w4;
#pragma unroll
        for (int i = 0; i < 4; ++i) Wacc[et][i] *= gC;
      }
      // stage next chunk's scaled v^T
      if (vrole && ch + 1 < NC_) write_vTs();
      // land next group's tile (other buffer -- safe since its readers done)
      if (g + 1 < NC_ * 8) write_pf((g + 1) & 1);
      __syncthreads();                 // #2: Wb/red/vTs/tile ready
      // reduce 4 k-range partials (overlaps next chunk's compute)
      if (tid < 256) {
        int c = tid >> 2, dq = tid & 3;
        f32x4 sum = *(const f32x4*)&red[0][c][dq * 4];
#pragma unroll
        for (int p = 1; p < 4; ++p) sum += *(const f32x4*)&red[p][c][dq * 4];
        float sc = EXP2F(lg2g * (float)c);
        short4v o;
#pragma unroll
        for (int i = 0; i < 4; ++i) o[i] = f2bfs(sum[i] * sc);
        *(short4v*)(inter_ + (size_t)b * T_ * D_ + (size_t)(ch * 64 + c) * D_ + d0 + dq * 4) = o;
      }
    }
  }
}

// ---------------------------------------------------------------- intra chunk
__global__ __launch_bounds__(256) void k_intra(const short* __restrict__ rk,
                                               const short* __restrict__ vT_g,
                                               short* __restrict__ intra_,
                                               const float* __restrict__ decay_p) {
  __shared__ short rs[65][264];
  __shared__ short P[64][72];
  __shared__ short vs[256][72];
  const int tid = threadIdx.x;
  const int lane = tid & 63, wv = tid >> 6;
  const int l16 = lane & 15, q = lane >> 4;
  const int ch = blockIdx.x, b = blockIdx.y;
  const int t0 = ch << 6;
  const float gamma = 1.f / (1.f + EXPF(-decay_p[0]));
  const float lg2g = LOG2F(gamma);
  const short* rk_b = rk + (size_t)b * T_ * D_;
  f32x4 Sacc[4];
#pragma unroll
  for (int j = 0; j < 4; ++j) Sacc[j] = (f32x4){0.f, 0.f, 0.f, 0.f};

  for (int s = 0; s < 4; ++s) {
    const int e0 = s << 8;
#pragma unroll
    for (int p = 0; p < 9; ++p) {
      int idx = p * 256 + tid;
      if (idx < 2080) {
        int row = idx >> 5, seg = idx & 31;
        int t = t0 - 1 + row;
        short8 v8;
        if (t >= 0) v8 = *(const short8*)(rk_b + (size_t)t * D_ + e0 + seg * 8);
        else v8 = (short8){0, 0, 0, 0, 0, 0, 0, 0};
        *(short8*)&rs[row][seg * 8] = v8;
      }
    }
    __syncthreads();
#pragma unroll
    for (int ks = 0; ks < 8; ++ks) {
      short8 af = *(const short8*)&rs[wv * 16 + l16 + 1][ks * 32 + q * 8];   // r rows
#pragma unroll
      for (int nt = 0; nt < 4; ++nt) {
        short8 bfr = *(const short8*)&rs[nt * 16 + l16][ks * 32 + q * 8];    // w rows
        Sacc[nt] = mfma16(af, bfr, Sacc[nt]);
      }
    }
    __syncthreads();
  }
  // mask: P[c][c'] = S * gamma^(c-1-c') for c>c', else 0
#pragma unroll
  for (int nt = 0; nt < 4; ++nt)
#pragma unroll
    for (int i = 0; i < 4; ++i) {
      int c = wv * 16 + q * 4 + i;
      int cp = nt * 16 + l16;
      float m = (c > cp) ? EXP2F(lg2g * (float)(c - 1 - cp)) : 0.f;
      P[c][cp] = f2bfs(Sacc[nt][i] * m);
    }
  __syncthreads();
  const short* vsrc = vT_g + (size_t)b * D_ * T_ + (size_t)tid * T_ + t0;
  size_t base = (size_t)b * T_ * D_;
  for (int p = 0; p < 4; ++p) {
    const short* sp = vsrc + (size_t)(p * 256) * T_;
#pragma unroll
    for (int seg = 0; seg < 8; ++seg)
      *(short8*)&vs[tid][seg * 8] = *(const short8*)(sp + seg * 8);
    __syncthreads();
    f32x4 acc[4][4];
#pragma unroll
    for (int a = 0; a < 4; ++a)
#pragma unroll
      for (int bb = 0; bb < 4; ++bb) acc[a][bb] = (f32x4){0.f, 0.f, 0.f, 0.f};
#pragma unroll
    for (int ks2 = 0; ks2 < 2; ++ks2) {
      short8 af[4];
#pragma unroll
      for (int mt = 0; mt < 4; ++mt) af[mt] = *(const short8*)&P[mt * 16 + l16][ks2 * 32 + q * 8];
#pragma unroll
      for (int nt = 0; nt < 4; ++nt) {
        short8 bfr = *(const short8*)&vs[wv * 64 + nt * 16 + l16][ks2 * 32 + q * 8];
#pragma unroll
        for (int mt = 0; mt < 4; ++mt) acc[mt][nt] = mfma16(af[mt], bfr, acc[mt][nt]);
      }
    }
#pragma unroll
    for (int mt = 0; mt < 4; ++mt)
#pragma unroll
      for (int nt = 0; nt < 4; ++nt)
#pragma unroll
        for (int i = 0; i < 4; ++i) {
          int c = mt * 16 + q * 4 + i;
          int d = p * 256 + wv * 64 + nt * 16 + l16;
          intra_[base + (size_t)(t0 + c) * D_ + d] = f2bfs(acc[mt][nt][i]);
        }
    __syncthreads();
  }
}

// ---------------------------------------------------------------- final GEMM
__global__ __launch_bounds__(256) void k_gemm_final(const short* __restrict__ inter_,
                                                    const short* __restrict__ intra_,
                                                    const short* __restrict__ Wr,
                                                    const float* __restrict__ xin,
                                                    float* __restrict__ y,
                                                    const float* __restrict__ la_p) {
  __shared__ short As[128][72];
  __shared__ short Bs[128][72];
  const float alpha = EXPF(la_p[0]);
  const int tid = threadIdx.x;
  const int lane = tid & 63, wv = tid >> 6;
  const int wm = (wv >> 1) * 64, wn = (wv & 1) * 64;
  const int l16 = lane & 15, q = lane >> 4;
  const int m0 = blockIdx.x * 128;
  const int n0 = blockIdx.y * 128;
  f32x4 acc[4][4];
  for (int a = 0; a < 4; ++a)
    for (int b = 0; b < 4; ++b) acc[a][b] = (f32x4){0.f, 0.f, 0.f, 0.f};
  const int lrow = tid >> 3, lseg = tid & 7;
  for (int kb = 0; kb < D_; kb += 64) {
#pragma unroll
    for (int p = 0; p < 4; ++p) {
      size_t aoff = (size_t)(m0 + lrow + p * 32) * D_ + kb + lseg * 8;
      short8 xa = *(const short8*)(inter_ + aoff);
      short8 xb = *(const short8*)(intra_ + aoff);
      short8 xs;
#pragma unroll
      for (int j = 0; j < 8; ++j) xs[j] = f2bfs(bf2fs(xa[j]) + bf2fs(xb[j]));
      *(short8*)&As[lrow + p * 32][lseg * 8] = xs;
      *(short8*)&Bs[lrow + p * 32][lseg * 8] =
          *(const short8*)(Wr + (size_t)(n0 + lrow + p * 32) * D_ + kb + lseg * 8);
    }
    __syncthreads();
#pragma unroll
    for (int ks = 0; ks < 2; ++ks) {
      short8 af[4], bfr[4];
#pragma unroll
      for (int mt = 0; mt < 4; ++mt) af[mt] = *(const short8*)&As[wm + mt * 16 + l16][ks * 32 + q * 8];
#pragma unroll
      for (int nt = 0; nt < 4; ++nt) bfr[nt] = *(const short8*)&Bs[wn + nt * 16 + l16][ks * 32 + q * 8];
#pragma unroll
      for (int mt = 0; mt < 4; ++mt)
#pragma unroll
        for (int nt = 0; nt < 4; ++nt) acc[mt][nt] = mfma16(af[mt], bfr[nt], acc[mt][nt]);
    }
    __syncthreads();
  }
#pragma unroll
  for (int mt = 0; mt < 4; ++mt)
#pragma unroll
    for (int nt = 0; nt < 4; ++nt)
#pragma unroll
      for (int i = 0; i < 4; ++i) {
        int t = m0 + wm + mt * 16 + q * 4 + i;
        int d = n0 + wn + nt * 16 + l16;
        size_t idx = (size_t)t * D_ + d;
        y[idx] = xin[idx] + alpha * acc[mt][nt][i];
      }
}

// ---------------------------------------------------------------- launch
extern "C" void kernel_launch(void* const* d_in, const int* in_sizes, int n_in,
                              void* d_out, int out_size, void* d_ws, size_t ws_size,
                              hipStream_t stream) {
  const float* x = (const float*)d_in[0];
  const float* Ww = (const float*)d_in[1];
  const float* Wr = (const float*)d_in[2];
  const float* decay = (const float*)d_in[3];
  const float* log_alpha = (const float*)d_in[4];
  float* y = (float*)d_out;

  short* ws = (short*)d_ws;
  const size_t NTD = (size_t)B_ * T_ * D_;   // 33,554,432
  short* rk_bf = ws;
  short* vT_bf = rk_bf + NTD;
  short* inter_b = vT_bf + NTD;
  short* intra_b = inter_b + NTD;
  short* Ww_bf = intra_b + NTD;
  short* Wr_bf = Ww_bf + (size_t)D_ * D_;
  // wTg aliases intra_b: only live between k_transT and k_scan; k_intra
  // overwrites it afterwards. total ws use unchanged: 4*NTD + 2*D*D shorts.
  short* wTg = intra_b;

  k_cast<<<(int)(NTD / 8 / 256), 256, 0, stream>>>(x, rk_bf, (int)(NTD / 8));
  k_cast<<<512, 256, 0, stream>>>(Ww, Ww_bf, (D_ * D_) / 8);
  k_cast<<<512, 256, 0, stream>>>(Wr, Wr_bf, (D_ * D_) / 8);
  k_transT<<<dim3(T_ / 64, D_ / 64, B_), 256, 0, stream>>>(rk_bf, wTg);
  k_gemm_v<<<dim3(256, 8), 256, 0, stream>>>(Ww_bf, rk_bf, vT_bf);
  k_scan<<<dim3(64, 4), 1024, 0, stream>>>(rk_bf, vT_bf, wTg, inter_b, decay);
  k_intra<<<dim3(128, 4), 256, 0, stream>>>(rk_bf, vT_bf, intra_b, decay);
  k_gemm_final<<<dim3(256, 8), 256, 0, stream>>>(inter_b, intra_b, Wr_bf, x, y, log_alpha);
}

// Round 6
// 941.201 us; speedup vs baseline: 1.7850x; 1.3587x over previous
//
#include <hip/hip_runtime.h>

// ---------------------------------------------------------------------------
// HebbianBlock: out(B,T,D) f32; chunked linear-attention style recurrence.
// Pipeline: cast->bf16 | w^T transpose | vT = Ww@rk^T (GEMM) |
//           scan(inter, W-state; dt=32, T-split P=2, XOR-swizzled LDS,
//                16 balanced waves, lgkm-only barriers) |
//           corr (seg-1 state correction GEMM) | intra |
//           y = out + alpha*(inter+intra)@Wr^T (GEMM)
// ---------------------------------------------------------------------------

typedef __attribute__((ext_vector_type(8))) short short8;
typedef __attribute__((ext_vector_type(4))) short short4v;
typedef __attribute__((ext_vector_type(4))) float f32x4;

#define B_ 4
#define T_ 8192
#define D_ 1024
#define C_ 64
#define NC_ 128
#define CHS_ 64     // chunks per T-segment (NC_/2)

#define DEVI static __device__ __forceinline__

#define EXPF(x) __builtin_expf(x)
#define LOG2F(x) __builtin_log2f(x)
#define EXP2F(x) __builtin_exp2f(x)

DEVI unsigned short f2bf_u(float f) {
  unsigned int u = __float_as_uint(f);
  u += 0x7fffu + ((u >> 16) & 1u);   // round-to-nearest-even
  return (unsigned short)(u >> 16);
}
DEVI short f2bfs(float f) { return (short)f2bf_u(f); }
DEVI float bf2fs(short h) { return __uint_as_float(((unsigned int)(unsigned short)h) << 16); }

DEVI f32x4 mfma16(short8 a, short8 b, f32x4 c) {
  return __builtin_amdgcn_mfma_f32_16x16x32_bf16(a, b, c, 0, 0, 0);
}

// bare workgroup barrier: drain ONLY LDS ops (writes visible to other waves);
// global register-loads stay in flight (no vmcnt(0) drain). R3 verified correct.
DEVI void chunk_barrier() {
  asm volatile("s_waitcnt lgkmcnt(0)" ::: "memory");
  __builtin_amdgcn_s_barrier();
}

// ---------------------------------------------------------------- cast f32->bf16
__global__ __launch_bounds__(256) void k_cast(const float* __restrict__ src,
                                              short* __restrict__ dst, int n8) {
  int i = blockIdx.x * 256 + threadIdx.x;
  if (i >= n8) return;
  const float4* s = (const float4*)src;
  float4 a = s[2 * i], b = s[2 * i + 1];
  short8 o;
  o[0] = f2bfs(a.x); o[1] = f2bfs(a.y); o[2] = f2bfs(a.z); o[3] = f2bfs(a.w);
  o[4] = f2bfs(b.x); o[5] = f2bfs(b.y); o[6] = f2bfs(b.z); o[7] = f2bfs(b.w);
  *((short8*)dst + i) = o;
}

// ---------------------------------------------------------------- w^T transpose
// wTg[b][e][t] = rk[b][t-1][e]  (pre-shifted: w_t = rk_{t-1}, t=0 -> 0)
__global__ __launch_bounds__(256) void k_transT(const short* __restrict__ rk,
                                                short* __restrict__ wTg) {
  __shared__ short ts[64][72];
  const int tid = threadIdx.x;
  const int t0 = blockIdx.x * 64, e0 = blockIdx.y * 64, b = blockIdx.z;
  const short* rk_b = rk + (size_t)b * T_ * D_;
  short* w_b = wTg + (size_t)b * D_ * T_;
  const int lr = tid >> 3, ls = tid & 7;   // 32 rows x 8 segs per pass
#pragma unroll
  for (int p = 0; p < 2; ++p) {
    int row = p * 32 + lr;                 // ts[row] holds rk[t0-1+row]
    int t = t0 - 1 + row;
    short8 v8;
    if (t >= 0) v8 = *(const short8*)(rk_b + (size_t)t * D_ + e0 + ls * 8);
    else v8 = (short8){0, 0, 0, 0, 0, 0, 0, 0};
    *(short8*)&ts[row][ls * 8] = v8;
  }
  __syncthreads();
  const int er5 = tid & 31, thi = tid >> 5;   // erow low-bits for bank spread
#pragma unroll
  for (int ep = 0; ep < 2; ++ep) {
    int erow = ep * 32 + er5;
    short8 w8;
#pragma unroll
    for (int j = 0; j < 8; ++j) w8[j] = ts[thi * 8 + j][erow];
    *(short8*)(w_b + (size_t)(e0 + erow) * T_ + t0 + thi * 8) = w8;
  }
}

// ---------------------------------------------------------------- vT = Ww @ rk^T
__global__ __launch_bounds__(256) void k_gemm_v(const short* __restrict__ Aw,
                                                const short* __restrict__ Bx,
                                                short* __restrict__ vT) {
  __shared__ short As[128][72];
  __shared__ short Bs[128][72];
  const int tid = threadIdx.x;
  const int lane = tid & 63, wv = tid >> 6;
  const int wm = (wv >> 1) * 64, wn = (wv & 1) * 64;
  const int l16 = lane & 15, q = lane >> 4;
  const int m0 = blockIdx.y * 128;
  const int n0 = blockIdx.x * 128;
  f32x4 acc[4][4];
  for (int a = 0; a < 4; ++a)
    for (int b = 0; b < 4; ++b) acc[a][b] = (f32x4){0.f, 0.f, 0.f, 0.f};
  const int lrow = tid >> 3, lseg = tid & 7;
  const short* Ap = Aw + (size_t)(m0 + lrow) * D_ + lseg * 8;
  const short* Bp = Bx + (size_t)(n0 + lrow) * D_ + lseg * 8;
  for (int kb = 0; kb < D_; kb += 64) {
#pragma unroll
    for (int p = 0; p < 4; ++p) {
      *(short8*)&As[lrow + p * 32][lseg * 8] = *(const short8*)(Ap + (size_t)(p * 32) * D_ + kb);
      *(short8*)&Bs[lrow + p * 32][lseg * 8] = *(const short8*)(Bp + (size_t)(p * 32) * D_ + kb);
    }
    __syncthreads();
#pragma unroll
    for (int ks = 0; ks < 2; ++ks) {
      short8 af[4], bfr[4];
#pragma unroll
      for (int mt = 0; mt < 4; ++mt) af[mt] = *(const short8*)&As[wm + mt * 16 + l16][ks * 32 + q * 8];
#pragma unroll
      for (int nt = 0; nt < 4; ++nt) bfr[nt] = *(const short8*)&Bs[wn + nt * 16 + l16][ks * 32 + q * 8];
#pragma unroll
      for (int mt = 0; mt < 4; ++mt)
#pragma unroll
        for (int nt = 0; nt < 4; ++nt) acc[mt][nt] = mfma16(af[mt], bfr[nt], acc[mt][nt]);
    }
    __syncthreads();
  }
  const int b = n0 >> 13;                // T_ = 8192 rows per batch
  const int tbase = (n0 & (T_ - 1)) + wn;
  short* outp = vT + (size_t)b * D_ * T_;
#pragma unroll
  for (int mt = 0; mt < 4; ++mt)
#pragma unroll
    for (int nt = 0; nt < 4; ++nt)
#pragma unroll
      for (int i = 0; i < 4; ++i) {
        int d = m0 + wm + mt * 16 + q * 4 + i;
        int t = tbase + nt * 16 + l16;
        outp[(size_t)d * T_ + t] = f2bfs(acc[mt][nt][i]);
      }
}

// ---------------------------------------------------------------- scan (inter + W state)
// grid (32 d-tiles, 4 batches, 2 T-segments), 1024 threads (16 waves).
// Block owns W[d0:d0+32][0:1024] in 32 f32 regs/thread; scans 64 chunks.
// Per chunk: 8 slice-groups of 128 e; rs/wT staged global->reg->LDS (dbuf,
// XOR-swizzled 16B units, 1 lgkm-barrier/group).
// GEMM1 (inter): wave = (dsub=wv>>3, ct=(wv>>1)&3, krp=wv&1), 2 MFMA/group.
// GEMM2 (W^T):   wave = (dh=wv>>3, et=wv&7), 2 MFMA/group into Wacc[s].
// Segment 0 writes its final state W_64 to Sg for k_corr.
__global__ __launch_bounds__(1024, 4) void k_scan(const short* __restrict__ rk,
                                                  const short* __restrict__ vT_g,
                                                  const short* __restrict__ wTg,
                                                  short* __restrict__ inter_,
                                                  short* __restrict__ Sg,
                                                  const float* __restrict__ decay_p) {
  __shared__ short rs[2][64][128];    // r rows (c) x 128 e, XOR-swz units
  __shared__ short wTs_[2][128][64];  // w^T rows (e) x 64 c, XOR-swz units
  __shared__ short Wb[32][1024];      // bf16 snapshot W[d][e], XOR-swz units
  __shared__ short vTs[32][72];       // v^T slice scaled by gw[c]=gamma^(63-c)
  __shared__ float red[2][64][36];    // inter partials [krp][c][d32+pad]

  const int tid = threadIdx.x;
  const int lane = tid & 63;
  const int wv = tid >> 6;                 // 0..15
  const int l16 = lane & 15, q = lane >> 4;
  const int dt = blockIdx.x, b = blockIdx.y, sg = blockIdx.z;
  const int d0 = dt * 32;
  const int tseg0 = sg * (CHS_ * 64);      // 0 or 4096
  const float gamma = 1.f / (1.f + EXPF(-decay_p[0]));
  const float lg2g = LOG2F(gamma);
  const float gC = EXP2F(64.f * lg2g);

  const short* rk_b = rk + (size_t)b * T_ * D_;
  const short* wT_b = wTg + (size_t)b * D_ * T_;
  const short* vT_b = vT_g + (size_t)b * D_ * T_;

  const int dsub = wv >> 3, ct = (wv >> 1) & 3, krp = wv & 1;   // GEMM1 roles
  const int dh = wv >> 3, et = wv & 7;                           // GEMM2 roles
  const int l7 = l16 & 7;

  // staging geometry (1024 threads move 16 KB rs + 16 KB wT per group)
  const int arow = tid >> 4, aunit = tid & 15;   // rs: 64 rows x 16 units
  const int wrow = tid >> 3, wunit = tid & 7;    // wT: 128 rows x 8 units
  const short* aG = rk_b + (size_t)(tseg0 + arow) * D_ + aunit * 8;
  const short* wG = wT_b + (size_t)wrow * T_ + tseg0 + wunit * 8;
  const int asw = (aunit ^ (arow & 7)) * 8;
  const int wsw = (wunit ^ (wrow & 7)) * 8;

  // vTs staging: threads [512,1024) stage 32 d-rows x 64 c
  const bool vrole = (tid >= 512);
  const int vd = (tid - 512) >> 4;               // 0..31
  const int vc4 = ((tid - 512) & 15) << 2;
  const short* vptr = vT_b + (size_t)(d0 + vd) * T_ + tseg0 + vc4;
  short4v vpre;

  f32x4 Wacc[8];                     // W^T[e = s*128+et*16+q*4+i][d = dh*16+l16]
#pragma unroll
  for (int j = 0; j < 8; ++j) Wacc[j] = (f32x4){0.f, 0.f, 0.f, 0.f};
  f32x4 iacc = (f32x4){0.f, 0.f, 0.f, 0.f};  // inter[d=dsub*16+q*4+i][c=ct*16+l16]

  short8 pfA, pfW;
  auto issue = [&](int g2) {               // g2 = ch*8 + s
    int nch = g2 >> 3, ns = g2 & 7;
    pfA = *(const short8*)(aG + (size_t)(nch * 64) * D_ + ns * 128);
    pfW = *(const short8*)(wG + (size_t)(ns * 128) * T_ + nch * 64);
  };
  auto write_pf = [&](int buf) {
    *(short8*)&rs[buf][arow][asw] = pfA;
    *(short8*)&wTs_[buf][wrow][wsw] = pfW;
  };
  auto write_vTs = [&]() {
#pragma unroll
    for (int j = 0; j < 4; ++j)
      vTs[vd][vc4 + j] = f2bfs(bf2fs(vpre[j]) * EXP2F(lg2g * (float)(63 - (vc4 + j))));
  };

  // ---- prologue: stage group 0, zero Wb, vTs(ch0), issue group 1
  issue(0);
  if (vrole) vpre = *(const short4v*)vptr;
  write_pf(0);
  if (vrole) write_vTs();
  {
    short4v z4 = (short4v){0, 0, 0, 0};
#pragma unroll
    for (int i = 0; i < 8; ++i) ((short4v*)&Wb[0][0])[tid + i * 1024] = z4;
  }
  issue(1);
  __syncthreads();

  short8 a2k0, a2k1;
  for (int ch = 0; ch < CHS_; ++ch) {
#pragma unroll
    for (int s = 0; s < 8; ++s) {
      const int g = ch * 8 + s;
      const int cur = s & 1;
      if (s == 0) {
        // v^T B-fragments for this chunk (vTs written at prev epilogue)
        a2k0 = *(const short8*)&vTs[dh * 16 + l16][q * 8];
        a2k1 = *(const short8*)&vTs[dh * 16 + l16][32 + q * 8];
        if (vrole) {
          int chn = (ch + 1 < CHS_) ? ch + 1 : ch;
          vpre = *(const short4v*)(vptr + chn * 64);
        }
      }
      // land tile for g+1 (loaded during g-1), then start loads for g+2
      if (g + 1 < CHS_ * 8) write_pf((s + 1) & 1);
      if (g + 2 < CHS_ * 8) issue(g + 2);
      // GEMM1: inter += Wb-frag (A, d rows) x r-frag (B, c rows)
#pragma unroll
      for (int u = 0; u < 2; ++u) {
        int kr = krp * 2 + u;
        short8 af = *(const short8*)&rs[cur][ct * 16 + l16][((kr * 4 + q) ^ l7) * 8];
        short8 bfr = *(const short8*)&Wb[dsub * 16 + l16][((s * 16 + kr * 4 + q) ^ l7) * 8];
        iacc = mfma16(bfr, af, iacc);
      }
      // GEMM2: W^T[e][d] += wT-frag (A, e rows) x vg-frag (B, d rows)
      {
        short8 bw0 = *(const short8*)&wTs_[cur][et * 16 + l16][(q ^ l7) * 8];
        short8 bw1 = *(const short8*)&wTs_[cur][et * 16 + l16][((4 + q) ^ l7) * 8];
        Wacc[s] = mfma16(bw0, a2k0, Wacc[s]);
        Wacc[s] = mfma16(bw1, a2k1, Wacc[s]);
      }
      chunk_barrier();   // end of group: staged tile visible, reads done
    }
    // ---- chunk epilogue ----
    // inter partial dump + reset
    *(f32x4*)&red[krp][ct * 16 + l16][dsub * 16 + q * 4] = iacc;
    iacc = (f32x4){0.f, 0.f, 0.f, 0.f};
    // W snapshot (pre-decay) -> Wb[d][e] (swizzled); then decay state
    {
      const int row_d = dh * 16 + l16;
#pragma unroll
      for (int s2 = 0; s2 < 8; ++s2) {
        short4v w4;
#pragma unroll
        for (int i = 0; i < 4; ++i) w4[i] = f2bfs(Wacc[s2][i]);
        int e_base = s2 * 128 + et * 16 + q * 4;
        int unit = e_base >> 3;
        *(short4v*)&Wb[row_d][((unit ^ l7) << 3) + (e_base & 7)] = w4;
        if (sg == 0 && ch == CHS_ - 1)   // segment-0 final state -> Sg
          *(short4v*)(Sg + ((size_t)b * D_ + d0 + row_d) * D_ + e_base) = w4;
#pragma unroll
        for (int i = 0; i < 4; ++i) Wacc[s2][i] *= gC;
      }
    }
    if (vrole && ch + 1 < CHS_) write_vTs();
    chunk_barrier();   // Wb/red/vTs ready
    // reduce 2 krp partials, scale by gamma^c, store bf16 (waves 0-3)
    if (tid < 256) {
      int c = tid >> 2, dq = tid & 3;
      f32x4 s0 = *(const f32x4*)&red[0][c][dq * 8];
      f32x4 s1 = *(const f32x4*)&red[0][c][dq * 8 + 4];
      s0 += *(const f32x4*)&red[1][c][dq * 8];
      s1 += *(const f32x4*)&red[1][c][dq * 8 + 4];
      float sc = EXP2F(lg2g * (float)c);
      short8 o;
#pragma unroll
      for (int i = 0; i < 4; ++i) { o[i] = f2bfs(s0[i] * sc); o[4 + i] = f2bfs(s1[i] * sc); }
      *(short8*)(inter_ + (size_t)b * T_ * D_ +
                 (size_t)(tseg0 + ch * 64 + c) * D_ + d0 + dq * 8) = o;
    }
  }
}

// ---------------------------------------------------------------- seg-1 correction
// inter[b][4096+lt][d] += gamma^lt * sum_e rk[b][4096+lt][e] * Sg[b][d][e],
// for lt in [0,2048) (gamma^2048 ~ 1e-9: below bf16 resolution -> skipped).
__global__ __launch_bounds__(256) void k_corr(const short* __restrict__ rk,
                                              const short* __restrict__ Sg,
                                              short* __restrict__ inter_,
                                              const float* __restrict__ decay_p) {
  __shared__ short As[128][72];
  __shared__ short Bs[128][72];
  const int tid = threadIdx.x;
  const int lane = tid & 63, wv = tid >> 6;
  const int wm = (wv >> 1) * 64, wn = (wv & 1) * 64;
  const int l16 = lane & 15, q = lane >> 4;
  const int m0 = blockIdx.x * 128;         // lt tile
  const int n0 = blockIdx.y * 128;         // d tile
  const int b = blockIdx.z;
  const float gamma = 1.f / (1.f + EXPF(-decay_p[0]));
  const float lg2g = LOG2F(gamma);
  const short* Ab = rk + (size_t)b * T_ * D_ + (size_t)(4096 + m0) * D_;
  const short* Bb = Sg + (size_t)b * D_ * D_ + (size_t)n0 * D_;
  f32x4 acc[4][4];
  for (int a = 0; a < 4; ++a)
    for (int c = 0; c < 4; ++c) acc[a][c] = (f32x4){0.f, 0.f, 0.f, 0.f};
  const int lrow = tid >> 3, lseg = tid & 7;
  for (int kb = 0; kb < D_; kb += 64) {
#pragma unroll
    for (int p = 0; p < 4; ++p) {
      *(short8*)&As[lrow + p * 32][lseg * 8] =
          *(const short8*)(Ab + (size_t)(lrow + p * 32) * D_ + kb + lseg * 8);
      *(short8*)&Bs[lrow + p * 32][lseg * 8] =
          *(const short8*)(Bb + (size_t)(lrow + p * 32) * D_ + kb + lseg * 8);
    }
    __syncthreads();
#pragma unroll
    for (int ks = 0; ks < 2; ++ks) {
      short8 af[4], bfr[4];
#pragma unroll
      for (int mt = 0; mt < 4; ++mt) af[mt] = *(const short8*)&As[wm + mt * 16 + l16][ks * 32 + q * 8];
#pragma unroll
      for (int nt = 0; nt < 4; ++nt) bfr[nt] = *(const short8*)&Bs[wn + nt * 16 + l16][ks * 32 + q * 8];
#pragma unroll
      for (int mt = 0; mt < 4; ++mt)
#pragma unroll
        for (int nt = 0; nt < 4; ++nt) acc[mt][nt] = mfma16(af[mt], bfr[nt], acc[mt][nt]);
    }
    __syncthreads();
  }
#pragma unroll
  for (int mt = 0; mt < 4; ++mt)
#pragma unroll
    for (int nt = 0; nt < 4; ++nt)
#pragma unroll
      for (int i = 0; i < 4; ++i) {
        int lt = m0 + wm + mt * 16 + q * 4 + i;
        int d = n0 + wn + nt * 16 + l16;
        size_t idx = (size_t)b * T_ * D_ + (size_t)(4096 + lt) * D_ + d;
        float cur = bf2fs(inter_[idx]);
        inter_[idx] = f2bfs(cur + acc[mt][nt][i] * EXP2F(lg2g * (float)lt));
      }
}

// ---------------------------------------------------------------- intra chunk
__global__ __launch_bounds__(256) void k_intra(const short* __restrict__ rk,
                                               const short* __restrict__ vT_g,
                                               short* __restrict__ intra_,
                                               const float* __restrict__ decay_p) {
  __shared__ short rs[65][264];
  __shared__ short P[64][72];
  __shared__ short vs[256][72];
  const int tid = threadIdx.x;
  const int lane = tid & 63, wv = tid >> 6;
  const int l16 = lane & 15, q = lane >> 4;
  const int ch = blockIdx.x, b = blockIdx.y;
  const int t0 = ch << 6;
  const float gamma = 1.f / (1.f + EXPF(-decay_p[0]));
  const float lg2g = LOG2F(gamma);
  const short* rk_b = rk + (size_t)b * T_ * D_;
  f32x4 Sacc[4];
#pragma unroll
  for (int j = 0; j < 4; ++j) Sacc[j] = (f32x4){0.f, 0.f, 0.f, 0.f};

  for (int s = 0; s < 4; ++s) {
    const int e0 = s << 8;
#pragma unroll
    for (int p = 0; p < 9; ++p) {
      int idx = p * 256 + tid;
      if (idx < 2080) {
        int row = idx >> 5, seg = idx & 31;
        int t = t0 - 1 + row;
        short8 v8;
        if (t >= 0) v8 = *(const short8*)(rk_b + (size_t)t * D_ + e0 + seg * 8);
        else v8 = (short8){0, 0, 0, 0, 0, 0, 0, 0};
        *(short8*)&rs[row][seg * 8] = v8;
      }
    }
    __syncthreads();
#pragma unroll
    for (int ks = 0; ks < 8; ++ks) {
      short8 af = *(const short8*)&rs[wv * 16 + l16 + 1][ks * 32 + q * 8];   // r rows
#pragma unroll
      for (int nt = 0; nt < 4; ++nt) {
        short8 bfr = *(const short8*)&rs[nt * 16 + l16][ks * 32 + q * 8];    // w rows
        Sacc[nt] = mfma16(af, bfr, Sacc[nt]);
      }
    }
    __syncthreads();
  }
  // mask: P[c][c'] = S * gamma^(c-1-c') for c>c', else 0
#pragma unroll
  for (int nt = 0; nt < 4; ++nt)
#pragma unroll
    for (int i = 0; i < 4; ++i) {
      int c = wv * 16 + q * 4 + i;
      int cp = nt * 16 + l16;
      float m = (c > cp) ? EXP2F(lg2g * (float)(c - 1 - cp)) : 0.f;
      P[c][cp] = f2bfs(Sacc[nt][i] * m);
    }
  __syncthreads();
  const short* vsrc = vT_g + (size_t)b * D_ * T_ + (size_t)tid * T_ + t0;
  size_t base = (size_t)b * T_ * D_;
  for (int p = 0; p < 4; ++p) {
    const short* sp = vsrc + (size_t)(p * 256) * T_;
#pragma unroll
    for (int seg = 0; seg < 8; ++seg)
      *(short8*)&vs[tid][seg * 8] = *(const short8*)(sp + seg * 8);
    __syncthreads();
    f32x4 acc[4][4];
#pragma unroll
    for (int a = 0; a < 4; ++a)
#pragma unroll
      for (int bb = 0; bb < 4; ++bb) acc[a][bb] = (f32x4){0.f, 0.f, 0.f, 0.f};
#pragma unroll
    for (int ks2 = 0; ks2 < 2; ++ks2) {
      short8 af[4];
#pragma unroll
      for (int mt = 0; mt < 4; ++mt) af[mt] = *(const short8*)&P[mt * 16 + l16][ks2 * 32 + q * 8];
#pragma unroll
      for (int nt = 0; nt < 4; ++nt) {
        short8 bfr = *(const short8*)&vs[wv * 64 + nt * 16 + l16][ks2 * 32 + q * 8];
#pragma unroll
        for (int mt = 0; mt < 4; ++mt) acc[mt][nt] = mfma16(af[mt], bfr, acc[mt][nt]);
      }
    }
#pragma unroll
    for (int mt = 0; mt < 4; ++mt)
#pragma unroll
      for (int nt = 0; nt < 4; ++nt)
#pragma unroll
        for (int i = 0; i < 4; ++i) {
          int c = mt * 16 + q * 4 + i;
          int d = p * 256 + wv * 64 + nt * 16 + l16;
          intra_[base + (size_t)(t0 + c) * D_ + d] = f2bfs(acc[mt][nt][i]);
        }
    __syncthreads();
  }
}

// ---------------------------------------------------------------- final GEMM
__global__ __launch_bounds__(256) void k_gemm_final(const short* __restrict__ inter_,
                                                    const short* __restrict__ intra_,
                                                    const short* __restrict__ Wr,
                                                    const float* __restrict__ xin,
                                                    float* __restrict__ y,
                                                    const float* __restrict__ la_p) {
  __shared__ short As[128][72];
  __shared__ short Bs[128][72];
  const float alpha = EXPF(la_p[0]);
  const int tid = threadIdx.x;
  const int lane = tid & 63, wv = tid >> 6;
  const int wm = (wv >> 1) * 64, wn = (wv & 1) * 64;
  const int l16 = lane & 15, q = lane >> 4;
  const int m0 = blockIdx.x * 128;
  const int n0 = blockIdx.y * 128;
  f32x4 acc[4][4];
  for (int a = 0; a < 4; ++a)
    for (int b = 0; b < 4; ++b) acc[a][b] = (f32x4){0.f, 0.f, 0.f, 0.f};
  const int lrow = tid >> 3, lseg = tid & 7;
  for (int kb = 0; kb < D_; kb += 64) {
#pragma unroll
    for (int p = 0; p < 4; ++p) {
      size_t aoff = (size_t)(m0 + lrow + p * 32) * D_ + kb + lseg * 8;
      short8 xa = *(const short8*)(inter_ + aoff);
      short8 xb = *(const short8*)(intra_ + aoff);
      short8 xs;
#pragma unroll
      for (int j = 0; j < 8; ++j) xs[j] = f2bfs(bf2fs(xa[j]) + bf2fs(xb[j]));
      *(short8*)&As[lrow + p * 32][lseg * 8] = xs;
      *(short8*)&Bs[lrow + p * 32][lseg * 8] =
          *(const short8*)(Wr + (size_t)(n0 + lrow + p * 32) * D_ + kb + lseg * 8);
    }
    __syncthreads();
#pragma unroll
    for (int ks = 0; ks < 2; ++ks) {
      short8 af[4], bfr[4];
#pragma unroll
      for (int mt = 0; mt < 4; ++mt) af[mt] = *(const short8*)&As[wm + mt * 16 + l16][ks * 32 + q * 8];
#pragma unroll
      for (int nt = 0; nt < 4; ++nt) bfr[nt] = *(const short8*)&Bs[wn + nt * 16 + l16][ks * 32 + q * 8];
#pragma unroll
      for (int mt = 0; mt < 4; ++mt)
#pragma unroll
        for (int nt = 0; nt < 4; ++nt) acc[mt][nt] = mfma16(af[mt], bfr[nt], acc[mt][nt]);
    }
    __syncthreads();
  }
#pragma unroll
  for (int mt = 0; mt < 4; ++mt)
#pragma unroll
    for (int nt = 0; nt < 4; ++nt)
#pragma unroll
      for (int i = 0; i < 4; ++i) {
        int t = m0 + wm + mt * 16 + q * 4 + i;
        int d = n0 + wn + nt * 16 + l16;
        size_t idx = (size_t)t * D_ + d;
        y[idx] = xin[idx] + alpha * acc[mt][nt][i];
      }
}

// ---------------------------------------------------------------- launch
extern "C" void kernel_launch(void* const* d_in, const int* in_sizes, int n_in,
                              void* d_out, int out_size, void* d_ws, size_t ws_size,
                              hipStream_t stream) {
  const float* x = (const float*)d_in[0];
  const float* Ww = (const float*)d_in[1];
  const float* Wr = (const float*)d_in[2];
  const float* decay = (const float*)d_in[3];
  const float* log_alpha = (const float*)d_in[4];
  float* y = (float*)d_out;

  short* ws = (short*)d_ws;
  const size_t NTD = (size_t)B_ * T_ * D_;   // 33,554,432
  short* rk_bf = ws;
  short* vT_bf = rk_bf + NTD;
  short* inter_b = vT_bf + NTD;
  short* intra_b = inter_b + NTD;
  short* Ww_bf = intra_b + NTD;
  short* Wr_bf = Ww_bf + (size_t)D_ * D_;
  short* Sg = Wr_bf + (size_t)D_ * D_;       // B x D x D bf16 (8 MB)
  // wTg aliases intra_b: only live between k_transT and k_scan; k_intra
  // overwrites it afterwards. total ws: 4*NTD + (2+B)*D*D shorts ~ 281 MB.
  short* wTg = intra_b;

  k_cast<<<(int)(NTD / 8 / 256), 256, 0, stream>>>(x, rk_bf, (int)(NTD / 8));
  k_cast<<<512, 256, 0, stream>>>(Ww, Ww_bf, (D_ * D_) / 8);
  k_cast<<<512, 256, 0, stream>>>(Wr, Wr_bf, (D_ * D_) / 8);
  k_transT<<<dim3(T_ / 64, D_ / 64, B_), 256, 0, stream>>>(rk_bf, wTg);
  k_gemm_v<<<dim3(256, 8), 256, 0, stream>>>(Ww_bf, rk_bf, vT_bf);
  k_scan<<<dim3(32, 4, 2), 1024, 0, stream>>>(rk_bf, vT_bf, wTg, inter_b, Sg, decay);
  k_corr<<<dim3(16, 8, 4), 256, 0, stream>>>(rk_bf, Sg, inter_b, decay);
  k_intra<<<dim3(128, 4), 256, 0, stream>>>(rk_bf, vT_bf, intra_b, decay);
  k_gemm_final<<<dim3(256, 8), 256, 0, stream>>>(inter_b, intra_b, Wr_bf, x, y, log_alpha);
}